// Round 9
// baseline (200.887 us; speedup 1.0000x reference)
//
#include <hip/hip_runtime.h>
#include <hip/hip_bf16.h>

typedef __attribute__((ext_vector_type(8))) short short8;     // 8 bf16 (MFMA A/B frag, K=32)
typedef __attribute__((ext_vector_type(4))) float float4v;    // MFMA C/D frag
typedef __attribute__((ext_vector_type(4))) _Float16 half4;   // f16 A/B frag, K=16
typedef __attribute__((ext_vector_type(2))) __fp16 fp16x2;    // cvt_pkrtz result type

// ---------------------------------------------------------------------------
// fp32 -> bf16 elementwise convert (vectorized: 4 floats -> 4 bf16 per thread)
// ---------------------------------------------------------------------------
__global__ __launch_bounds__(256) void cvt_f32_bf16(
    const float* __restrict__ in, __hip_bfloat16* __restrict__ out, int n4) {
  const int i = blockIdx.x * 256 + threadIdx.x;
  if (i >= n4) return;
  const float4 v = *(const float4*)(in + (size_t)i * 4);
  __hip_bfloat16 o[4];
  o[0] = __float2bfloat16(v.x); o[1] = __float2bfloat16(v.y);
  o[2] = __float2bfloat16(v.z); o[3] = __float2bfloat16(v.w);
  *(uint2*)(out + (size_t)i * 4) = *(const uint2*)o;
}

// ---------------------------------------------------------------------------
// Transpose + convert: in fp32 (R x C) -> out bf16 (C x R). R,C mult of 32.
// ---------------------------------------------------------------------------
__global__ __launch_bounds__(256) void transpose_f32_bf16(
    const float* __restrict__ in, __hip_bfloat16* __restrict__ out,
    int R, int C) {
  __shared__ __hip_bfloat16 tile[32][33];
  const int c0 = blockIdx.x * 32, r0 = blockIdx.y * 32;
  const int tx = threadIdx.x & 31, ty = threadIdx.x >> 5;  // 256 thr: ty 0..7
  #pragma unroll
  for (int i = ty; i < 32; i += 8)
    tile[i][tx] = __float2bfloat16(in[(size_t)(r0 + i) * C + (c0 + tx)]);
  __syncthreads();
  #pragma unroll
  for (int i = ty; i < 32; i += 8)
    out[(size_t)(c0 + i) * R + (r0 + tx)] = tile[tx][i];
}

// ---------------------------------------------------------------------------
// gemm_bt: C (MxN, OutT) = A (MxK, row-major bf16) @ Bt^T  (Bt is NxK bf16)
// 128x128 tile, BK=64, 256 threads = 4 waves. m97-style global_load_lds
// width=16 staging, stride-64 LDS with XOR chunk swizzle. (r6: 2x+ win; frozen)
// ---------------------------------------------------------------------------
template <typename OutT>
__global__ __launch_bounds__(256) void gemm_bt(
    const __hip_bfloat16* __restrict__ A,
    const __hip_bfloat16* __restrict__ Bt,
    OutT* __restrict__ C,
    int M, int N, int K) {
  __shared__ __hip_bfloat16 lA[128][64];
  __shared__ __hip_bfloat16 lB[128][64];
  const int t = threadIdx.x;
  const int lane = t & 63, wave = t >> 6;
  const int quad = lane >> 4, ln = lane & 15;
  const int m0 = blockIdx.y * 128, n0 = blockIdx.x * 128;
  const int wm = (wave >> 1) * 64, wn = (wave & 1) * 64;
  const int srow = lane >> 3;                    // 0..7
  const int schunk = ((lane & 7) ^ srow) * 8;    // swizzled elem offset

  float4v acc[4][4];
  #pragma unroll
  for (int i = 0; i < 4; ++i)
    #pragma unroll
    for (int j = 0; j < 4; ++j)
      acc[i][j] = (float4v){0.f, 0.f, 0.f, 0.f};

  for (int kt = 0; kt < K; kt += 64) {
    __syncthreads();   // previous iter's frag reads done before DMA overwrite
    #pragma unroll
    for (int q = 0; q < 4; ++q) {
      const int rbase = wave * 32 + q * 8;       // wave-uniform 8-row group
      __builtin_amdgcn_global_load_lds(
          (const __attribute__((address_space(1))) void*)
              (A + (size_t)(m0 + rbase + srow) * K + kt + schunk),
          (__attribute__((address_space(3))) void*)&lA[rbase][0], 16, 0, 0);
      __builtin_amdgcn_global_load_lds(
          (const __attribute__((address_space(1))) void*)
              (Bt + (size_t)(n0 + rbase + srow) * K + kt + schunk),
          (__attribute__((address_space(3))) void*)&lB[rbase][0], 16, 0, 0);
    }
    __syncthreads();   // vmcnt(0) drain: DMA complete, LDS visible
    #pragma unroll
    for (int step = 0; step < 2; ++step) {
      short8 af[4], bf[4];
      #pragma unroll
      for (int i = 0; i < 4; ++i)
        af[i] = *(const short8*)&lA[wm + i * 16 + ln][((step * 4 + quad) ^ (ln & 7)) * 8];
      #pragma unroll
      for (int j = 0; j < 4; ++j)
        bf[j] = *(const short8*)&lB[wn + j * 16 + ln][((step * 4 + quad) ^ (ln & 7)) * 8];
      #pragma unroll
      for (int i = 0; i < 4; ++i)
        #pragma unroll
        for (int j = 0; j < 4; ++j)
          acc[i][j] = __builtin_amdgcn_mfma_f32_16x16x32_bf16(af[i], bf[j], acc[i][j], 0, 0, 0);
    }
  }
  // Epilogue. C/D layout: row = quad*4 + reg, col = lane&15 (m89/m91-verified).
  #pragma unroll
  for (int i = 0; i < 4; ++i)
    #pragma unroll
    for (int j = 0; j < 4; ++j)
      #pragma unroll
      for (int r = 0; r < 4; ++r) {
        const int row = m0 + wm + i * 16 + quad * 4 + r;
        const int col = n0 + wn + j * 16 + ln;
        if constexpr (__is_same(OutT, float))
          C[(size_t)row * N + col] = acc[i][j][r];
        else
          C[(size_t)row * N + col] = __float2bfloat16(acc[i][j][r]);
      }
}

// ---------------------------------------------------------------------------
// RoPE + reshape: qkv (4096 x 3072 bf16) -> Q, K as (b,h,s,d) = (32, 2048, 64)
// Q scaled by (1/sqrt(64)) * log2(e): attention computes scores in the exp2
// domain, so P = exp2(S') == exp(S/8) with a single v_exp_f32 (no mul).
// ---------------------------------------------------------------------------
__global__ __launch_bounds__(512) void rope_reshape(
    const __hip_bfloat16* __restrict__ qkv,
    __hip_bfloat16* __restrict__ Q,
    __hip_bfloat16* __restrict__ K) {
  const int row = blockIdx.x;          // b*2048 + s
  const int s = row & 2047;
  const int b = row >> 11;
  const int t = threadIdx.x;
  const int h = t >> 5, pr = t & 31;
  const int d0 = pr * 2;
  const float freq = powf(10000.f, -(float)d0 / 64.f);
  const float ang = (float)s * freq;
  float sn, cs;
  sincosf(ang, &sn, &cs);
  const float qs = 0.125f * 1.44269504088896340736f;  // (1/8)*log2(e)

  const size_t in_base = (size_t)row * 3072;
  const size_t o = (((size_t)(b * 16 + h)) * 2048 + s) * 64 + d0;

  __hip_bfloat162 q2 = *(const __hip_bfloat162*)&qkv[in_base + h * 64 + d0];
  float x1 = __bfloat162float(q2.x), x2 = __bfloat162float(q2.y);
  __hip_bfloat162 qo;
  qo.x = __float2bfloat16((x1 * cs - x2 * sn) * qs);
  qo.y = __float2bfloat16((x1 * sn + x2 * cs) * qs);
  *(__hip_bfloat162*)&Q[o] = qo;

  __hip_bfloat162 k2 = *(const __hip_bfloat162*)&qkv[in_base + 1024 + h * 64 + d0];
  x1 = __bfloat162float(k2.x); x2 = __bfloat162float(k2.y);
  __hip_bfloat162 ko;
  ko.x = __float2bfloat16(x1 * cs - x2 * sn);
  ko.y = __float2bfloat16(x1 * sn + x2 * cs);
  *(__hip_bfloat162*)&K[o] = ko;
}

// ---------------------------------------------------------------------------
// V transpose + f16 convert: qkv v-part -> Vt (b,h,d,s) f16 = (32, 64, 2048).
// f16 (not bf16): V values are small-range; f16's 10-bit mantissa beats bf16,
// and the attention PV stage consumes f16 fragments (K=16 f16 MFMA).
// ---------------------------------------------------------------------------
__global__ __launch_bounds__(256) void v_transpose(
    const __hip_bfloat16* __restrict__ qkv,
    _Float16* __restrict__ Vt) {
  __shared__ _Float16 tile[64][65];
  const int bh = blockIdx.y;
  const int h = bh & 15, b = bh >> 4;
  const int s0 = blockIdx.x * 64;
  const int tx = threadIdx.x & 63, ty = threadIdx.x >> 6;  // ty 0..3
  #pragma unroll
  for (int i = ty; i < 64; i += 4)
    tile[i][tx] = (_Float16)__bfloat162float(
        qkv[(size_t)(b * 2048 + s0 + i) * 3072 + 2048 + h * 64 + tx]);
  __syncthreads();
  #pragma unroll
  for (int i = ty; i < 64; i += 4)
    Vt[((size_t)bh * 64 + i) * 2048 + s0 + tx] = tile[tx][i];
}

// ---------------------------------------------------------------------------
// Flash-style causal attention, fixed-max softmax, paired q-tiles, dbuf DMA
// (r7 pipeline) -- now computing S^T = K*Q^T so the exp'd C-frags feed the
// PV stage DIRECTLY as the B-operand of mfma_f32_16x16x16f16 (C-layout row =
// quad*4+reg  ==  K=16 B-layout k = quad*4+j). No LDS round-trip for P.
//   QK^T: A = K-frags (m=sk), B = Q-frags (n=q), 16x16x32 bf16 -> S^T C-frags
//   PV:   O^T[d][q]: A = V^T-frags from lV[d][sk] (m=d, k=sk contiguous b64),
//         B = P^T = cvt_pkrtz(exp2(S^T)), 16x16x16 f16, 4 sk-chunks
//   l:    5th MFMA with A = ones -> every lane holds l[q=ln] directly
// Scores in exp2 domain (Q pre-scaled by log2e/8). Masked scores = -64:
// exp2(-64)=5e-20 flushes to +0 in f16. Epilogue: 4 contiguous bf16 per store.
// ---------------------------------------------------------------------------
__global__ __launch_bounds__(256) void attention(
    const __hip_bfloat16* __restrict__ Q,
    const __hip_bfloat16* __restrict__ K,
    const _Float16* __restrict__ Vt,
    __hip_bfloat16* __restrict__ attn) {
  __shared__ __hip_bfloat16 lK[2][64][64];    // [buf][sk][d]   XOR-swizzled
  __shared__ _Float16       lV[2][64][64];    // [buf][d][sk]   XOR-swizzled
  const int t = threadIdx.x;
  const int lane = t & 63, w = t >> 6;
  const int quad = lane >> 4, ln = lane & 15;
  const int bh = blockIdx.x;                  // id%8 = bh%8 -> XCD locality
  const int pair = blockIdx.y;
  const size_t base = (size_t)bh * 2048 * 64;
  const __hip_bfloat16* Qb = Q + base;
  const __hip_bfloat16* Kb = K + base;
  const _Float16* Vb = Vt + base;
  const int b = bh >> 4, h = bh & 15;

  half4 vones;
  #pragma unroll
  for (int i = 0; i < 4; ++i) vones[i] = (_Float16)1.0f;

  const int srow = lane >> 3;                    // 0..7
  const int schunk = ((lane & 7) ^ srow) * 8;    // swizzled elem offset
  const int rb0 = w * 16;                        // this wave's 16-row share

  #pragma unroll
  for (int ph = 0; ph < 2; ++ph) {
    const int qt = (ph == 0) ? pair : 31 - pair;
    const int q0 = qt * 64;

    __syncthreads();   // protect buf0 from previous phase's last compute

    // stage kt=0 into buf 0 (each wave: 2 K-row-groups + 2 V-row-groups)
    #pragma unroll
    for (int g = 0; g < 2; ++g) {
      const int rbase = rb0 + g * 8;
      __builtin_amdgcn_global_load_lds(
          (const __attribute__((address_space(1))) void*)
              (Kb + (size_t)(rbase + srow) * 64 + schunk),
          (__attribute__((address_space(3))) void*)&lK[0][rbase][0], 16, 0, 0);
      __builtin_amdgcn_global_load_lds(
          (const __attribute__((address_space(1))) void*)
              (Vb + (size_t)(rbase + srow) * 2048 + schunk),
          (__attribute__((address_space(3))) void*)&lV[0][rbase][0], 16, 0, 0);
    }

    // Q fragment (B-operand now; same per-lane layout): n = ln, k = quad*8+j
    short8 qf[2];
    {
      const size_t qrow = (size_t)(q0 + w * 16 + ln) * 64;
      qf[0] = *(const short8*)(Qb + qrow + quad * 8);
      qf[1] = *(const short8*)(Qb + qrow + 32 + quad * 8);
    }

    float4v acc_o[4];   // O^T: rows d = dt*16+quad*4+r, col q = ln
    #pragma unroll
    for (int dt = 0; dt < 4; ++dt) acc_o[dt] = (float4v){0.f, 0.f, 0.f, 0.f};
    float4v acc_l = (float4v){0.f, 0.f, 0.f, 0.f};   // every reg = l[q=ln]

    for (int kt = 0; kt <= qt; ++kt) {
      const int buf = kt & 1;
      __syncthreads();   // drains DMA(kt); frees buf^1

      if (kt < qt) {     // prefetch kt+1 into the other buffer — after barrier
        #pragma unroll
        for (int g = 0; g < 2; ++g) {
          const int rbase = rb0 + g * 8;
          __builtin_amdgcn_global_load_lds(
              (const __attribute__((address_space(1))) void*)
                  (Kb + (size_t)((kt + 1) * 64 + rbase + srow) * 64 + schunk),
              (__attribute__((address_space(3))) void*)&lK[buf ^ 1][rbase][0], 16, 0, 0);
          __builtin_amdgcn_global_load_lds(
              (const __attribute__((address_space(1))) void*)
                  (Vb + (size_t)(rbase + srow) * 2048 + (kt + 1) * 64 + schunk),
              (__attribute__((address_space(3))) void*)&lV[buf ^ 1][rbase][0], 16, 0, 0);
        }
      }

      // S^T = K Q^T: A = K-frag (m = sk = nt*16+ln), B = qf
      float4v s4[4];
      #pragma unroll
      for (int nt = 0; nt < 4; ++nt) {
        float4v a = (float4v){0.f, 0.f, 0.f, 0.f};
        #pragma unroll
        for (int step = 0; step < 2; ++step) {
          short8 kf = *(const short8*)&lK[buf][nt * 16 + ln][((step * 4 + quad) ^ (ln & 7)) * 8];
          a = __builtin_amdgcn_mfma_f32_16x16x32_bf16(kf, qf[step], a, 0, 0, 0);
        }
        s4[nt] = a;
      }
      if (kt == qt) {  // diagonal tile: causal mask (rows sk = quad*4+r now)
        #pragma unroll
        for (int nt = 0; nt < 4; ++nt)
          #pragma unroll
          for (int r = 0; r < 4; ++r) {
            const int sk = kt * 64 + nt * 16 + quad * 4 + r;
            const int qr = q0 + w * 16 + ln;
            if (sk > qr) s4[nt][r] = -64.f;
          }
      }
      // P^T = exp2(S^T) -> f16 B-frags (C-layout == K=16 B-layout), no LDS
      half4 pf[4];
      #pragma unroll
      for (int nt = 0; nt < 4; ++nt) {
        const fp16x2 lo = __builtin_amdgcn_cvt_pkrtz(exp2f(s4[nt][0]), exp2f(s4[nt][1]));
        const fp16x2 hi = __builtin_amdgcn_cvt_pkrtz(exp2f(s4[nt][2]), exp2f(s4[nt][3]));
        pf[nt][0] = (_Float16)lo[0]; pf[nt][1] = (_Float16)lo[1];
        pf[nt][2] = (_Float16)hi[0]; pf[nt][3] = (_Float16)hi[1];
      }
      // O^T += V^T P^T ; l += 1 P^T   (4 sk-chunks of 16, K=16 f16 MFMA)
      #pragma unroll
      for (int s = 0; s < 4; ++s) {
        acc_l = __builtin_amdgcn_mfma_f32_16x16x16f16(vones, pf[s], acc_l, 0, 0, 0);
        #pragma unroll
        for (int dt = 0; dt < 4; ++dt) {
          half4 vf = *(const half4*)&lV[buf][dt * 16 + ln]
              [((s * 2 + (quad >> 1)) ^ (ln & 7)) * 8 + (quad & 1) * 4];
          acc_o[dt] = __builtin_amdgcn_mfma_f32_16x16x16f16(vf, pf[s], acc_o[dt], 0, 0, 0);
        }
      }
    }

    // write O^T / l: lane owns q-row qr = q0+w*16+ln, d cols dt*16+quad*4+0..3
    const float inv_l = 1.0f / acc_l[0];
    const int qr = q0 + w * 16 + ln;
    const size_t rg = (size_t)(b * 2048 + qr) * 1024 + h * 64;
    #pragma unroll
    for (int dt = 0; dt < 4; ++dt) {
      __hip_bfloat16 o4[4];
      #pragma unroll
      for (int r = 0; r < 4; ++r)
        o4[r] = __float2bfloat16(acc_o[dt][r] * inv_l);
      *(uint2*)&attn[rg + dt * 16 + quad * 4] = *(const uint2*)o4;
    }
  }
}

// ---------------------------------------------------------------------------
extern "C" void kernel_launch(void* const* d_in, const int* in_sizes, int n_in,
                              void* d_out, int out_size, void* d_ws, size_t ws_size,
                              hipStream_t stream) {
  const float* x    = (const float*)d_in[0];  // (2,2048,1024) fp32
  const float* Wqkv = (const float*)d_in[1];  // (1024,3072)   fp32
  const float* Wout = (const float*)d_in[2];  // (1024,1024)   fp32
  float* out = (float*)d_out;                 // (2,2048,1024) fp32

  __hip_bfloat16* ws = (__hip_bfloat16*)d_ws;
  __hip_bfloat16* xb    = ws;                          // 4096*1024
  __hip_bfloat16* WqkvT = xb    + (size_t)4096 * 1024; // 3072*1024
  __hip_bfloat16* WoutT = WqkvT + (size_t)3072 * 1024; // 1024*1024
  __hip_bfloat16* qkv   = WoutT + (size_t)1024 * 1024; // 4096*3072
  __hip_bfloat16* Q     = qkv   + (size_t)4096 * 3072; // 32*2048*64
  __hip_bfloat16* K     = Q     + (size_t)32 * 2048 * 64;
  _Float16*       Vt    = (_Float16*)(K + (size_t)32 * 2048 * 64);
  __hip_bfloat16* attn  = (__hip_bfloat16*)(Vt + (size_t)32 * 2048 * 64);

  cvt_f32_bf16<<<4096, 256, 0, stream>>>(x, xb, 4096 * 1024 / 4);
  transpose_f32_bf16<<<dim3(3072 / 32, 1024 / 32), 256, 0, stream>>>(Wqkv, WqkvT, 1024, 3072);
  transpose_f32_bf16<<<dim3(1024 / 32, 1024 / 32), 256, 0, stream>>>(Wout, WoutT, 1024, 1024);
  gemm_bt<__hip_bfloat16><<<dim3(3072 / 128, 4096 / 128), 256, 0, stream>>>(xb, WqkvT, qkv, 4096, 3072, 1024);
  rope_reshape<<<4096, 512, 0, stream>>>(qkv, Q, K);
  v_transpose<<<dim3(32, 32), 256, 0, stream>>>(qkv, Vt);
  attention<<<dim3(32, 16), 256, 0, stream>>>(Q, K, Vt, attn);
  gemm_bt<float><<<dim3(1024 / 128, 4096 / 128), 256, 0, stream>>>(attn, WoutT, out, 4096, 1024, 1024);
}